// Round 10
// baseline (7554.355 us; speedup 1.0000x reference)
//
#include <hip/hip_runtime.h>

// DeepLSTM persistent wavefront pipeline for MI355X (gfx950).
// 256 WGs (1/CU): layer = blockIdx/64, slice of 8 hidden units = blockIdx%64.
// Weights resident in LDS as hi/lo bf16 split. Control path = sc0/sc1 bypass;
// h data loads = plain cached (read-once ring addresses -> no staleness).
// R10: barrier-free hop (R9) with the two serial-chain fixes:
//  - 64-lane in-wave epilogue: 16 rows x 4 units per wave = 1 chain/lane
//    (R9 put 4 chains on 16 lanes -> VALU tail doubled the hop's serial part)
//  - merged dual-poll: input flag (t,l-1) and recurrent flag (t-1,l) become
//    ready simultaneously in steady state; detect both with ONE vmcnt, then
//    issue BOTH 16KB panel loads back-to-back so their latencies overlap.

constexpr int Bv = 32;
constexpr int Tv = 512;
constexpr int Iv = 256;
constexpr int Hv = 512;
constexpr int LAYv = 4;
constexpr int SLICES = 64;   // WGs per layer
constexpr int THREADS = 256; // 4 waves
constexpr int NKK = 32;      // K/32 total (512 recurrent + 512 input)
constexpr int WTAB = 2 * NKK * 64 * 8;  // shorts per weight table
constexpr int SCR_STRIDE = 20;          // scratch row stride (words)
constexpr unsigned SMEM_BYTES = WTAB * 2 * 2 + 4 * 16 * SCR_STRIDE * 4; // 136192

typedef short sfrag __attribute__((ext_vector_type(8)));
typedef float facc  __attribute__((ext_vector_type(4)));
typedef float f32x4 __attribute__((ext_vector_type(4)));

struct Params {
  const float *x;
  const float *Wx0i, *Wx0f, *Wx0o, *Wx0c;
  const float *Wxi, *Wxf, *Wxo, *Wxc;
  const float *Whi, *Whf, *Who, *Whc;
  const float *bi, *bf, *bo, *bc;
  float *out;
  unsigned short *hbuf;  // ring [512 t-slots][L][B][H] bf16, read-once
  unsigned char *flags;  // [Tv][L][2 mt][SLICES*2 (slice,nt)], write-once
  int dmask;
};

__device__ __forceinline__ unsigned short f2bf(float f) {
  unsigned int u = __builtin_bit_cast(unsigned int, f);
  u += 0x7FFFu + ((u >> 16) & 1u); // RNE
  return (unsigned short)(u >> 16);
}
__device__ __forceinline__ float bf2f(unsigned short s) {
  unsigned int u = ((unsigned int)s) << 16;
  return __builtin_bit_cast(float, u);
}

// ---- bypass (L1+L2) control-path primitives ----
// dual ushort flag load: both RTs overlap under one vmcnt
__device__ __forceinline__ void ld2_flag_bypass(const unsigned char *p0,
                                                const unsigned char *p1,
                                                int &a, int &b) {
  asm volatile("global_load_ushort %0, %2, off sc0 sc1\n\t"
               "global_load_ushort %1, %3, off sc0 sc1\n\t"
               "s_waitcnt vmcnt(0)"
               : "=&v"(a), "=&v"(b)
               : "v"(p0), "v"(p1)
               : "memory");
}
__device__ __forceinline__ void st_flagb_bypass(unsigned char *p) {
  asm volatile("global_store_byte %0, %1, off sc0 sc1" ::"v"(p), "v"(1)
               : "memory");
}
__device__ __forceinline__ void st_short_bypass(unsigned short *p, unsigned short v) {
  asm volatile("global_store_short %0, %1, off sc0 sc1" ::"v"(p), "v"(v)
               : "memory");
}

__global__ void __launch_bounds__(THREADS, 1) lstm_pipeline(Params p) {
  const int wg = blockIdx.x;
  const int l = wg >> 6;       // layer 0..3
  const int slice = wg & 63;   // 8-unit slice
  const int tid = threadIdx.x;
  const int lane = tid & 63;
  const int w = tid >> 6;      // wave 0..3
  const int mt = w & 1;        // M-tile (batch 16-block)
  const int nt = w >> 1;       // N-tile (gate-col 16-block)

  extern __shared__ char smem[];
  unsigned short *wlds_hi = (unsigned short *)smem;       // [2][32][64][8]
  unsigned short *wlds_lo = wlds_hi + WTAB;
  float *scratch = (float *)(smem + (size_t)WTAB * 2 * 2) +
                   (size_t)w * 16 * SCR_STRIDE;           // wave-private [16][20]

  // gate-indexed weight bases for this layer
  const float *Wh[4] = {p.Whi + (size_t)l * Hv * Hv, p.Whf + (size_t)l * Hv * Hv,
                        p.Who + (size_t)l * Hv * Hv, p.Whc + (size_t)l * Hv * Hv};
  const float *Wx[4];
  if (l == 0) { Wx[0] = p.Wx0i; Wx[1] = p.Wx0f; Wx[2] = p.Wx0o; Wx[3] = p.Wx0c; }
  else {
    size_t o = (size_t)(l - 1) * Hv * Hv;
    Wx[0] = p.Wxi + o; Wx[1] = p.Wxf + o; Wx[2] = p.Wxo + o; Wx[3] = p.Wxc + o;
  }
  const int kx_max = (l == 0) ? Iv : Hv;

  // ---- stage weight slice into LDS in MFMA B-fragment order (hi/lo split) ----
  for (int idx = tid; idx < 2 * NKK * 64; idx += THREADS) {
    int lanei = idx & 63;
    int kk = (idx >> 6) & (NKK - 1);
    int nti = idx >> 11;
    int kbase = kk * 32 + (lanei >> 4) * 8;
    int n = nti * 16 + (lanei & 15); // gate-col within 32: n = jj*4 + g
    int jj = n >> 2, g = n & 3;
    int col = slice * 8 + jj;
    sfrag vh, vl;
#pragma unroll
    for (int j = 0; j < 8; ++j) {
      int k = kbase + j;
      float wv;
      if (k < Hv) wv = Wh[g][(size_t)k * Hv + col];
      else {
        int kx = k - Hv;
        wv = (kx < kx_max) ? Wx[g][(size_t)kx * Hv + col] : 0.f;
      }
      unsigned short h16 = f2bf(wv);
      vh[j] = (short)h16;
      vl[j] = (short)f2bf(wv - bf2f(h16));
    }
    *(sfrag *)&wlds_hi[(size_t)idx * 8] = vh;
    *(sfrag *)&wlds_lo[(size_t)idx * 8] = vl;
  }

  // epilogue mapping: one (row, unit) pair per lane
  const int er = lane >> 2;          // local row 0..15
  const int eu = lane & 3;           // local unit 0..3
  const int ubase = slice * 8 + nt * 4;
  const int ju = ubase + eu;         // global unit column
  const int grow = mt * 16 + er;     // global batch row
  const float bia_i = p.bi[l * Hv + ju];
  const float bia_f = p.bf[l * Hv + ju];
  const float bia_o = p.bo[l * Hv + ju];
  const float bia_c = p.bc[l * Hv + ju];
  float cst = 0.f;

  __syncthreads(); // weights staged (the only barrier in the kernel)

  const int m = mt * 16 + (lane & 15); // batch row for A fragment
  const int kgrp = lane >> 4;          // k-group 0..3
  unsigned char *flags = p.flags;
  unsigned short *hbuf = p.hbuf;
  const int dmask = p.dmask;

#define MFMA_BURST(A, KKB, CNT)                                                \
  {                                                                            \
    _Pragma("unroll") for (int j = 0; j < (CNT); ++j) {                        \
      sfrag bh =                                                               \
          *(const sfrag *)&wlds_hi[(size_t)((nt * NKK + (KKB) + j) * 64 + lane) * 8]; \
      sfrag bl =                                                               \
          *(const sfrag *)&wlds_lo[(size_t)((nt * NKK + (KKB) + j) * 64 + lane) * 8]; \
      acc0 = __builtin_amdgcn_mfma_f32_16x16x32_bf16(A[j], bh, acc0, 0, 0, 0); \
      acc1 = __builtin_amdgcn_mfma_f32_16x16x32_bf16(A[j], bl, acc1, 0, 0, 0); \
    }                                                                          \
  }

  for (int t = 0; t < Tv; ++t) {
    facc acc0 = {0.f, 0.f, 0.f, 0.f};
    facc acc1 = {0.f, 0.f, 0.f, 0.f};

    // ---- merged dual poll: detect both dependencies under ONE vmcnt ----
    if (t > 0 || l > 0) {
      const unsigned char *fin =
          (l > 0) ? flags + ((size_t)(t * LAYv + (l - 1)) * 2 + mt) * 128 + lane * 2
                  : nullptr;
      const unsigned char *frec =
          (t > 0) ? flags + ((size_t)((t - 1) * LAYv + l) * 2 + mt) * 128 + lane * 2
                  : nullptr;
      const unsigned char *pa_ = fin ? fin : frec;
      const unsigned char *pb_ = frec ? frec : fin;
      int a, b;
      ld2_flag_bypass(pa_, pb_, a, b);
      while (a != 0x0101 || b != 0x0101) {
        __builtin_amdgcn_s_sleep(1);
        ld2_flag_bypass(pa_, pb_, a, b);
      }
    }

    // ---- issue BOTH panel loads back-to-back (latencies overlap) ----
    sfrag arec[16];
    if (t > 0) {
      const unsigned short *hrec =
          hbuf + ((size_t)((t & dmask) * LAYv + l) * Bv * Hv) + (size_t)m * Hv;
#pragma unroll
      for (int kk = 0; kk < 16; ++kk)
        arec[kk] = *(const sfrag *)(hrec + kk * 32 + kgrp * 8);
    }

    if (l > 0) {
      const unsigned short *hin =
          hbuf + ((size_t)(((t + 1) & dmask) * LAYv + (l - 1)) * Bv * Hv) +
          (size_t)m * Hv;
      sfrag ain[16];
#pragma unroll
      for (int kk = 0; kk < 16; ++kk)
        ain[kk] = *(const sfrag *)(hin + kk * 32 + kgrp * 8);
      MFMA_BURST(ain, 16, 16)
    } else {
      const float *xbp = p.x + ((size_t)m * Tv + t) * Iv + kgrp * 8;
#pragma unroll
      for (int kk = 0; kk < 8; ++kk) {
        f32x4 lo = *(const f32x4 *)(xbp + kk * 32);
        f32x4 hi = *(const f32x4 *)(xbp + kk * 32 + 4);
        sfrag ax;
#pragma unroll
        for (int j = 0; j < 4; ++j) {
          ax[j] = (short)f2bf(lo[j]);
          ax[4 + j] = (short)f2bf(hi[j]);
        }
        sfrag bh = *(const sfrag *)&wlds_hi[(size_t)((nt * NKK + 16 + kk) * 64 + lane) * 8];
        sfrag bl = *(const sfrag *)&wlds_lo[(size_t)((nt * NKK + 16 + kk) * 64 + lane) * 8];
        acc0 = __builtin_amdgcn_mfma_f32_16x16x32_bf16(ax, bh, acc0, 0, 0, 0);
        acc1 = __builtin_amdgcn_mfma_f32_16x16x32_bf16(ax, bl, acc1, 0, 0, 0);
      }
    }

    if (t > 0) { MFMA_BURST(arec, 0, 16) } // t==0: h=0 contributes nothing

    // ---- in-wave transpose via wave-private scratch (no barrier) ----
    {
      int rl = (lane >> 4) * 4;   // local row base of this lane's 4 acc rows
      int cl = lane & 15;         // local col (unit*4 + gate)
#pragma unroll
      for (int r = 0; r < 4; ++r)
        scratch[(rl + r) * SCR_STRIDE + cl] = acc0[r] + acc1[r];
    }
    // lgkmcnt ordering within the wave makes this read safe (same wave)
    f32x4 q = *(const f32x4 *)&scratch[er * SCR_STRIDE + eu * 4];

    // ---- gates / state update: ONE chain per lane (64 active lanes) ----
    float pi = q[0] + bia_i;
    float pf = q[1] + bia_f;
    float po = q[2] + bia_o;
    float pc = q[3] + bia_c;
    float gi = 1.f / (1.f + __expf(-pi));
    float gf = 1.f / (1.f + __expf(-pf));
    float go = 1.f / (1.f + __expf(-po));
    float gc = tanhf(pc);
    cst = gf * cst + gi * gc;
    float hval = go * tanhf(cst);

    // bypass store h[t+1]; per-WAVE drain; per-(wave) flag; out last
    st_short_bypass(&hbuf[((size_t)(((t + 1) & dmask) * LAYv + l) * Bv * Hv) +
                          (size_t)grow * Hv + ju],
                    f2bf(hval));
    asm volatile("s_waitcnt vmcnt(0)" ::: "memory"); // wave's stores at MALL
    if (lane == 0)
      st_flagb_bypass(flags + ((size_t)(t * LAYv + l) * 2 + mt) * 128 +
                      slice * 2 + nt);
    if (l == LAYv - 1)
      p.out[((size_t)grow * Tv + t) * Hv + ju] = hval;
  }
#undef MFMA_BURST
}

extern "C" void kernel_launch(void *const *d_in, const int *in_sizes, int n_in,
                              void *d_out, int out_size, void *d_ws, size_t ws_size,
                              hipStream_t stream) {
  Params prm;
  prm.x = (const float *)d_in[0];
  prm.Wx0i = (const float *)d_in[1];
  prm.Wx0f = (const float *)d_in[2];
  prm.Wx0o = (const float *)d_in[3];
  prm.Wx0c = (const float *)d_in[4];
  prm.Wxi = (const float *)d_in[5];
  prm.Wxf = (const float *)d_in[6];
  prm.Wxo = (const float *)d_in[7];
  prm.Wxc = (const float *)d_in[8];
  prm.Whi = (const float *)d_in[9];
  prm.Whf = (const float *)d_in[10];
  prm.Who = (const float *)d_in[11];
  prm.Whc = (const float *)d_in[12];
  prm.bi = (const float *)d_in[13];
  prm.bf = (const float *)d_in[14];
  prm.bo = (const float *)d_in[15];
  prm.bc = (const float *)d_in[16];
  prm.out = (float *)d_out;

  size_t slot_bytes = (size_t)LAYv * Bv * Hv * sizeof(unsigned short); // 128KB
  size_t fbytes = (size_t)Tv * LAYv * 2 * 128;                         // 512KB
  size_t hslots = 512; // exactly-once-read ring
  if (ws_size < hslots * slot_bytes + fbytes) {
    hslots = 256;
    if (ws_size < hslots * slot_bytes + fbytes) return;
  }
  prm.dmask = (int)hslots - 1;
  prm.hbuf = (unsigned short *)d_ws;
  prm.flags = (unsigned char *)d_ws + hslots * slot_bytes;

  // write-once flags, cleared every call (deterministic replays)
  hipMemsetAsync(prm.flags, 0, fbytes, stream);

  hipFuncSetAttribute(reinterpret_cast<const void *>(lstm_pipeline),
                      hipFuncAttributeMaxDynamicSharedMemorySize, (int)SMEM_BYTES);

  // Plain launch: 136KB LDS forces 1 block/CU; grid == 256 == #CUs.
  hipLaunchKernelGGL(lstm_pipeline, dim3(LAYv * SLICES), dim3(THREADS),
                     SMEM_BYTES, stream, prm);
}

// Round 11
// 5439.000 us; speedup vs baseline: 1.3889x; 1.3889x over previous
//
#include <hip/hip_runtime.h>

// DeepLSTM persistent wavefront pipeline for MI355X (gfx950).
// 256 WGs (1/CU): layer = blockIdx/64, slice of 8 hidden units = blockIdx%64.
// Weights resident in LDS as hi/lo bf16 split. Control path = sc0/sc1 bypass;
// h data loads = plain cached (read-once ring addresses -> no staleness).
// R11 = R8 ordering (input work BEFORE recurrent poll -- pacemaker-safe)
//  + barrier-free 64-lane in-wave epilogue (1 transcendental chain/lane)
//  + layer-0 x prefetch at iteration end (HBM latency lands inside the
//    next recurrent-poll wait, which exists anyway)
//  + recurrent panel loads issued before input MFMA so their latency hides
//    under it (l>0).

constexpr int Bv = 32;
constexpr int Tv = 512;
constexpr int Iv = 256;
constexpr int Hv = 512;
constexpr int LAYv = 4;
constexpr int SLICES = 64;   // WGs per layer
constexpr int THREADS = 256; // 4 waves
constexpr int NKK = 32;      // K/32 total (512 recurrent + 512 input)
constexpr int WTAB = 2 * NKK * 64 * 8;  // shorts per weight table
constexpr int SCR_STRIDE = 20;          // scratch row stride (words)
constexpr unsigned SMEM_BYTES = WTAB * 2 * 2 + 4 * 16 * SCR_STRIDE * 4; // 136192

typedef short sfrag __attribute__((ext_vector_type(8)));
typedef float facc  __attribute__((ext_vector_type(4)));
typedef float f32x4 __attribute__((ext_vector_type(4)));

struct Params {
  const float *x;
  const float *Wx0i, *Wx0f, *Wx0o, *Wx0c;
  const float *Wxi, *Wxf, *Wxo, *Wxc;
  const float *Whi, *Whf, *Who, *Whc;
  const float *bi, *bf, *bo, *bc;
  float *out;
  unsigned short *hbuf;  // ring [512 t-slots][L][B][H] bf16, read-once
  unsigned char *flags;  // [Tv][L][2 mt][SLICES*2 (slice,nt)], write-once
  int dmask;
};

__device__ __forceinline__ unsigned short f2bf(float f) {
  unsigned int u = __builtin_bit_cast(unsigned int, f);
  u += 0x7FFFu + ((u >> 16) & 1u); // RNE
  return (unsigned short)(u >> 16);
}
__device__ __forceinline__ float bf2f(unsigned short s) {
  unsigned int u = ((unsigned int)s) << 16;
  return __builtin_bit_cast(float, u);
}

// ---- bypass (L1+L2) control-path primitives ----
__device__ __forceinline__ int ld_flag_ushort_bypass(const unsigned char *p) {
  int v;
  asm volatile("global_load_ushort %0, %1, off sc0 sc1\n\t"
               "s_waitcnt vmcnt(0)"
               : "=v"(v) : "v"(p) : "memory");
  return v;
}
__device__ __forceinline__ void st_flagb_bypass(unsigned char *p) {
  asm volatile("global_store_byte %0, %1, off sc0 sc1" ::"v"(p), "v"(1)
               : "memory");
}
__device__ __forceinline__ void st_short_bypass(unsigned short *p, unsigned short v) {
  asm volatile("global_store_short %0, %1, off sc0 sc1" ::"v"(p), "v"(v)
               : "memory");
}
// all 64 lanes poll one slice's ushort (both nt producer flags) until 0x0101
__device__ __forceinline__ void poll_line(const unsigned char *base) {
  while (ld_flag_ushort_bypass(base) != 0x0101) __builtin_amdgcn_s_sleep(1);
}

__global__ void __launch_bounds__(THREADS, 1) lstm_pipeline(Params p) {
  const int wg = blockIdx.x;
  const int l = wg >> 6;       // layer 0..3
  const int slice = wg & 63;   // 8-unit slice
  const int tid = threadIdx.x;
  const int lane = tid & 63;
  const int w = tid >> 6;      // wave 0..3
  const int mt = w & 1;        // M-tile (batch 16-block)
  const int nt = w >> 1;       // N-tile (gate-col 16-block)

  extern __shared__ char smem[];
  unsigned short *wlds_hi = (unsigned short *)smem;       // [2][32][64][8]
  unsigned short *wlds_lo = wlds_hi + WTAB;
  float *scratch = (float *)(smem + (size_t)WTAB * 2 * 2) +
                   (size_t)w * 16 * SCR_STRIDE;           // wave-private [16][20]

  // gate-indexed weight bases for this layer
  const float *Wh[4] = {p.Whi + (size_t)l * Hv * Hv, p.Whf + (size_t)l * Hv * Hv,
                        p.Who + (size_t)l * Hv * Hv, p.Whc + (size_t)l * Hv * Hv};
  const float *Wx[4];
  if (l == 0) { Wx[0] = p.Wx0i; Wx[1] = p.Wx0f; Wx[2] = p.Wx0o; Wx[3] = p.Wx0c; }
  else {
    size_t o = (size_t)(l - 1) * Hv * Hv;
    Wx[0] = p.Wxi + o; Wx[1] = p.Wxf + o; Wx[2] = p.Wxo + o; Wx[3] = p.Wxc + o;
  }
  const int kx_max = (l == 0) ? Iv : Hv;

  // ---- stage weight slice into LDS in MFMA B-fragment order (hi/lo split) ----
  for (int idx = tid; idx < 2 * NKK * 64; idx += THREADS) {
    int lanei = idx & 63;
    int kk = (idx >> 6) & (NKK - 1);
    int nti = idx >> 11;
    int kbase = kk * 32 + (lanei >> 4) * 8;
    int n = nti * 16 + (lanei & 15); // gate-col within 32: n = jj*4 + g
    int jj = n >> 2, g = n & 3;
    int col = slice * 8 + jj;
    sfrag vh, vl;
#pragma unroll
    for (int j = 0; j < 8; ++j) {
      int k = kbase + j;
      float wv;
      if (k < Hv) wv = Wh[g][(size_t)k * Hv + col];
      else {
        int kx = k - Hv;
        wv = (kx < kx_max) ? Wx[g][(size_t)kx * Hv + col] : 0.f;
      }
      unsigned short h16 = f2bf(wv);
      vh[j] = (short)h16;
      vl[j] = (short)f2bf(wv - bf2f(h16));
    }
    *(sfrag *)&wlds_hi[(size_t)idx * 8] = vh;
    *(sfrag *)&wlds_lo[(size_t)idx * 8] = vl;
  }

  // epilogue mapping: one (row, unit) pair per lane
  const int er = lane >> 2;          // local row 0..15
  const int eu = lane & 3;           // local unit 0..3
  const int ubase = slice * 8 + nt * 4;
  const int ju = ubase + eu;         // global unit column
  const int grow = mt * 16 + er;     // global batch row
  const float bia_i = p.bi[l * Hv + ju];
  const float bia_f = p.bf[l * Hv + ju];
  const float bia_o = p.bo[l * Hv + ju];
  const float bia_c = p.bc[l * Hv + ju];
  float cst = 0.f;

  __syncthreads(); // weights staged (the only barrier in the kernel)

  const int m = mt * 16 + (lane & 15); // batch row for A fragment
  const int kgrp = lane >> 4;          // k-group 0..3
  unsigned char *flags = p.flags;
  unsigned short *hbuf = p.hbuf;
  const int dmask = p.dmask;

#define MFMA_BURST(A, KKB, CNT)                                                \
  {                                                                            \
    _Pragma("unroll") for (int j = 0; j < (CNT); ++j) {                        \
      sfrag bh =                                                               \
          *(const sfrag *)&wlds_hi[(size_t)((nt * NKK + (KKB) + j) * 64 + lane) * 8]; \
      sfrag bl =                                                               \
          *(const sfrag *)&wlds_lo[(size_t)((nt * NKK + (KKB) + j) * 64 + lane) * 8]; \
      acc0 = __builtin_amdgcn_mfma_f32_16x16x32_bf16(A[j], bh, acc0, 0, 0, 0); \
      acc1 = __builtin_amdgcn_mfma_f32_16x16x32_bf16(A[j], bl, acc1, 0, 0, 0); \
    }                                                                          \
  }

  // layer-0 x prefetch registers (f32, converted at use)
  f32x4 xv[16];
  if (l == 0) {
    const float *xbp = p.x + ((size_t)m * Tv + 0) * Iv + kgrp * 8;
#pragma unroll
    for (int kk = 0; kk < 8; ++kk) {
      xv[2 * kk] = *(const f32x4 *)(xbp + kk * 32);
      xv[2 * kk + 1] = *(const f32x4 *)(xbp + kk * 32 + 4);
    }
  }

  for (int t = 0; t < Tv; ++t) {
    facc acc0 = {0.f, 0.f, 0.f, 0.f};
    facc acc1 = {0.f, 0.f, 0.f, 0.f};

    if (l == 0) {
      // ---- pacemaker: poll own-layer flag FIRST (xv already prefetched) ----
      sfrag arec[16];
      if (t > 0) {
        poll_line(flags + ((size_t)((t - 1) * LAYv + l) * 2 + mt) * 128 + lane * 2);
        const unsigned short *hrec =
            hbuf + ((size_t)((t & dmask) * LAYv + l) * Bv * Hv) + (size_t)m * Hv;
#pragma unroll
        for (int kk = 0; kk < 16; ++kk)   // issue; latency hides under x-GEMM
          arec[kk] = *(const sfrag *)(hrec + kk * 32 + kgrp * 8);
      }
      // x-GEMM from prefetched registers (no memory wait)
#pragma unroll
      for (int kk = 0; kk < 8; ++kk) {
        sfrag ax;
#pragma unroll
        for (int j = 0; j < 4; ++j) {
          ax[j] = (short)f2bf(xv[2 * kk][j]);
          ax[4 + j] = (short)f2bf(xv[2 * kk + 1][j]);
        }
        sfrag bh = *(const sfrag *)&wlds_hi[(size_t)((nt * NKK + 16 + kk) * 64 + lane) * 8];
        sfrag bl = *(const sfrag *)&wlds_lo[(size_t)((nt * NKK + 16 + kk) * 64 + lane) * 8];
        acc0 = __builtin_amdgcn_mfma_f32_16x16x32_bf16(ax, bh, acc0, 0, 0, 0);
        acc1 = __builtin_amdgcn_mfma_f32_16x16x32_bf16(ax, bl, acc1, 0, 0, 0);
      }
      if (t > 0) { MFMA_BURST(arec, 0, 16) }
    } else {
      // ---- input poll + panel, recurrent poll + panel, then both MFMAs ----
      poll_line(flags + ((size_t)(t * LAYv + (l - 1)) * 2 + mt) * 128 + lane * 2);
      const unsigned short *hin =
          hbuf + ((size_t)(((t + 1) & dmask) * LAYv + (l - 1)) * Bv * Hv) +
          (size_t)m * Hv;
      sfrag ain[16];
#pragma unroll
      for (int kk = 0; kk < 16; ++kk)
        ain[kk] = *(const sfrag *)(hin + kk * 32 + kgrp * 8);

      sfrag arec[16];
      if (t > 0) {
        poll_line(flags + ((size_t)((t - 1) * LAYv + l) * 2 + mt) * 128 + lane * 2);
        const unsigned short *hrec =
            hbuf + ((size_t)((t & dmask) * LAYv + l) * Bv * Hv) + (size_t)m * Hv;
#pragma unroll
        for (int kk = 0; kk < 16; ++kk)   // issue; latency hides under input MFMA
          arec[kk] = *(const sfrag *)(hrec + kk * 32 + kgrp * 8);
      }
      MFMA_BURST(ain, 16, 16)
      if (t > 0) { MFMA_BURST(arec, 0, 16) }
    }

    // ---- in-wave transpose via wave-private scratch (no barrier) ----
    {
      int rl = (lane >> 4) * 4;   // local row base of this lane's 4 acc rows
      int cl = lane & 15;         // local col (unit*4 + gate)
#pragma unroll
      for (int r = 0; r < 4; ++r)
        scratch[(rl + r) * SCR_STRIDE + cl] = acc0[r] + acc1[r];
    }
    // lgkmcnt ordering within the wave makes this read safe (same wave)
    f32x4 q = *(const f32x4 *)&scratch[er * SCR_STRIDE + eu * 4];

    // ---- gates / state update: ONE chain per lane (64 active lanes) ----
    float pi = q[0] + bia_i;
    float pf = q[1] + bia_f;
    float po = q[2] + bia_o;
    float pc = q[3] + bia_c;
    float gi = 1.f / (1.f + __expf(-pi));
    float gf = 1.f / (1.f + __expf(-pf));
    float go = 1.f / (1.f + __expf(-po));
    float gc = tanhf(pc);
    cst = gf * cst + gi * gc;
    float hval = go * tanhf(cst);

    // bypass store h[t+1]; per-WAVE drain; per-wave flag
    st_short_bypass(&hbuf[((size_t)(((t + 1) & dmask) * LAYv + l) * Bv * Hv) +
                          (size_t)grow * Hv + ju],
                    f2bf(hval));
    asm volatile("s_waitcnt vmcnt(0)" ::: "memory"); // wave's stores at MALL
    if (lane == 0)
      st_flagb_bypass(flags + ((size_t)(t * LAYv + l) * 2 + mt) * 128 +
                      slice * 2 + nt);

    // off-critical-path tail: out store, then next-t x prefetch (its HBM
    // latency lands inside the next recurrent-poll wait)
    if (l == LAYv - 1)
      p.out[((size_t)grow * Tv + t) * Hv + ju] = hval;
    if (l == 0 && t + 1 < Tv) {
      const float *xbp = p.x + ((size_t)m * Tv + (t + 1)) * Iv + kgrp * 8;
#pragma unroll
      for (int kk = 0; kk < 8; ++kk) {
        xv[2 * kk] = *(const f32x4 *)(xbp + kk * 32);
        xv[2 * kk + 1] = *(const f32x4 *)(xbp + kk * 32 + 4);
      }
    }
  }
#undef MFMA_BURST
}

extern "C" void kernel_launch(void *const *d_in, const int *in_sizes, int n_in,
                              void *d_out, int out_size, void *d_ws, size_t ws_size,
                              hipStream_t stream) {
  Params prm;
  prm.x = (const float *)d_in[0];
  prm.Wx0i = (const float *)d_in[1];
  prm.Wx0f = (const float *)d_in[2];
  prm.Wx0o = (const float *)d_in[3];
  prm.Wx0c = (const float *)d_in[4];
  prm.Wxi = (const float *)d_in[5];
  prm.Wxf = (const float *)d_in[6];
  prm.Wxo = (const float *)d_in[7];
  prm.Wxc = (const float *)d_in[8];
  prm.Whi = (const float *)d_in[9];
  prm.Whf = (const float *)d_in[10];
  prm.Who = (const float *)d_in[11];
  prm.Whc = (const float *)d_in[12];
  prm.bi = (const float *)d_in[13];
  prm.bf = (const float *)d_in[14];
  prm.bo = (const float *)d_in[15];
  prm.bc = (const float *)d_in[16];
  prm.out = (float *)d_out;

  size_t slot_bytes = (size_t)LAYv * Bv * Hv * sizeof(unsigned short); // 128KB
  size_t fbytes = (size_t)Tv * LAYv * 2 * 128;                         // 512KB
  size_t hslots = 512; // exactly-once-read ring
  if (ws_size < hslots * slot_bytes + fbytes) {
    hslots = 256;
    if (ws_size < hslots * slot_bytes + fbytes) return;
  }
  prm.dmask = (int)hslots - 1;
  prm.hbuf = (unsigned short *)d_ws;
  prm.flags = (unsigned char *)d_ws + hslots * slot_bytes;

  // write-once flags, cleared every call (deterministic replays)
  hipMemsetAsync(prm.flags, 0, fbytes, stream);

  hipFuncSetAttribute(reinterpret_cast<const void *>(lstm_pipeline),
                      hipFuncAttributeMaxDynamicSharedMemorySize, (int)SMEM_BYTES);

  // Plain launch: 136KB LDS forces 1 block/CU; grid == 256 == #CUs.
  hipLaunchKernelGGL(lstm_pipeline, dim3(LAYv * SLICES), dim3(THREADS),
                     SMEM_BYTES, stream, prm);
}

// Round 12
// 3491.527 us; speedup vs baseline: 2.1636x; 1.5578x over previous
//
#include <hip/hip_runtime.h>

// DeepLSTM persistent wavefront pipeline for MI355X (gfx950).
// 256 WGs (1/CU): layer = blockIdx/64, slice of 8 hidden units = blockIdx%64.
// Weights resident in LDS as hi/lo bf16 split. Control path = sc0/sc1 bypass;
// h data loads = plain cached (read-once ring addresses -> no staleness).
// R12 = EXACT R8 structure (best: 3522us) with ONE change: flag layout
// [t][l][half][slice][2 waves] so each consumer poll is a SINGLE bypass
// ushort load (R8's poll_pair did 2 serial byte polls = 2 serial MALL RTs,
// the 2nd only starting after the 1st succeeded). Layer-0 pacemaker saves
// ~1 RT/hop directly on the pipeline pace.

constexpr int Bv = 32;
constexpr int Tv = 512;
constexpr int Iv = 256;
constexpr int Hv = 512;
constexpr int LAYv = 4;
constexpr int SLICES = 64;   // WGs per layer
constexpr int THREADS = 256; // 4 waves
constexpr int NKK = 32;      // K/32 total (512 recurrent + 512 input)
constexpr int WTAB = 2 * NKK * 64 * 8;  // shorts per weight table
constexpr int PRE = 32 * 33;
constexpr unsigned SMEM_BYTES = WTAB * 2 * 2 + 2 * PRE * 4; // 139520

typedef short sfrag __attribute__((ext_vector_type(8)));
typedef float facc  __attribute__((ext_vector_type(4)));
typedef float f32x4 __attribute__((ext_vector_type(4)));

struct Params {
  const float *x;
  const float *Wx0i, *Wx0f, *Wx0o, *Wx0c;
  const float *Wxi, *Wxf, *Wxo, *Wxc;
  const float *Whi, *Whf, *Who, *Whc;
  const float *bi, *bf, *bo, *bc;
  float *out;
  unsigned short *hbuf;  // ring [512 t-slots][L][B][H] bf16, read-once
  unsigned char *flags;  // [Tv][L][2 half][64 slices][2 wavesub], write-once
  int dmask;
};

__device__ __forceinline__ unsigned short f2bf(float f) {
  unsigned int u = __builtin_bit_cast(unsigned int, f);
  u += 0x7FFFu + ((u >> 16) & 1u); // RNE
  return (unsigned short)(u >> 16);
}
__device__ __forceinline__ float bf2f(unsigned short s) {
  unsigned int u = ((unsigned int)s) << 16;
  return __builtin_bit_cast(float, u);
}

// ---- bypass (L1+L2) control-path primitives ----
__device__ __forceinline__ int ld_flag_ushort_bypass(const unsigned char *p) {
  int v;
  asm volatile("global_load_ushort %0, %1, off sc0 sc1\n\t"
               "s_waitcnt vmcnt(0)"
               : "=v"(v) : "v"(p) : "memory");
  return v;
}
__device__ __forceinline__ void st_flagb_bypass(unsigned char *p) {
  asm volatile("global_store_byte %0, %1, off sc0 sc1" ::"v"(p), "v"(1)
               : "memory");
}
__device__ __forceinline__ void st_short_bypass(unsigned short *p, unsigned short v) {
  asm volatile("global_store_short %0, %1, off sc0 sc1" ::"v"(p), "v"(v)
               : "memory");
}
// one ushort poll covers BOTH producer waves of one slice for this half
__device__ __forceinline__ void poll_line(const unsigned char *base) {
  while (ld_flag_ushort_bypass(base) != 0x0101) __builtin_amdgcn_s_sleep(1);
}

__global__ void __launch_bounds__(THREADS, 1) lstm_pipeline(Params p) {
  const int wg = blockIdx.x;
  const int l = wg >> 6;       // layer 0..3
  const int slice = wg & 63;   // 8-unit slice
  const int tid = threadIdx.x;
  const int lane = tid & 63;
  const int w = tid >> 6;      // wave 0..3
  const int mt = w & 1;        // M-tile (batch 16-block)
  const int nt = w >> 1;       // N-tile (gate-col 16-block)

  extern __shared__ char smem[];
  unsigned short *wlds_hi = (unsigned short *)smem;       // [2][32][64][8]
  unsigned short *wlds_lo = wlds_hi + WTAB;
  float *pre0 = (float *)(smem + (size_t)WTAB * 2 * 2);   // [2][32][33]

  // gate-indexed weight bases for this layer
  const float *Wh[4] = {p.Whi + (size_t)l * Hv * Hv, p.Whf + (size_t)l * Hv * Hv,
                        p.Who + (size_t)l * Hv * Hv, p.Whc + (size_t)l * Hv * Hv};
  const float *Wx[4];
  if (l == 0) { Wx[0] = p.Wx0i; Wx[1] = p.Wx0f; Wx[2] = p.Wx0o; Wx[3] = p.Wx0c; }
  else {
    size_t o = (size_t)(l - 1) * Hv * Hv;
    Wx[0] = p.Wxi + o; Wx[1] = p.Wxf + o; Wx[2] = p.Wxo + o; Wx[3] = p.Wxc + o;
  }
  const int kx_max = (l == 0) ? Iv : Hv;

  // ---- stage weight slice into LDS in MFMA B-fragment order (hi/lo split) ----
  for (int idx = tid; idx < 2 * NKK * 64; idx += THREADS) {
    int lanei = idx & 63;
    int kk = (idx >> 6) & (NKK - 1);
    int nti = idx >> 11;
    int kbase = kk * 32 + (lanei >> 4) * 8;
    int n = nti * 16 + (lanei & 15); // gate-col within 32: n = jj*4 + g
    int jj = n >> 2, g = n & 3;
    int col = slice * 8 + jj;
    sfrag vh, vl;
#pragma unroll
    for (int j = 0; j < 8; ++j) {
      int k = kbase + j;
      float wv;
      if (k < Hv) wv = Wh[g][(size_t)k * Hv + col];
      else {
        int kx = k - Hv;
        wv = (kx < kx_max) ? Wx[g][(size_t)kx * Hv + col] : 0.f;
      }
      unsigned short h16 = f2bf(wv);
      vh[j] = (short)h16;
      vl[j] = (short)f2bf(wv - bf2f(h16));
    }
    *(sfrag *)&wlds_hi[(size_t)idx * 8] = vh;
    *(sfrag *)&wlds_lo[(size_t)idx * 8] = vl;
  }

  // epilogue thread mapping: bm = batch, um = unit-in-slice
  const int bm = tid >> 3;
  const int um = tid & 7;
  const int jg = slice * 8 + um;
  const float bia_i = p.bi[l * Hv + jg];
  const float bia_f = p.bf[l * Hv + jg];
  const float bia_o = p.bo[l * Hv + jg];
  const float bia_c = p.bc[l * Hv + jg];
  float cstate = 0.f;

  __syncthreads();

  const int m = mt * 16 + (lane & 15); // batch row for A fragment
  const int kgrp = lane >> 4;          // k-group 0..3
  unsigned char *flags = p.flags;
  unsigned short *hbuf = p.hbuf;
  const int dmask = p.dmask;

#define MFMA_BURST(A, KKB, CNT)                                                \
  {                                                                            \
    _Pragma("unroll") for (int j = 0; j < (CNT); ++j) {                        \
      sfrag bh =                                                               \
          *(const sfrag *)&wlds_hi[(size_t)((nt * NKK + (KKB) + j) * 64 + lane) * 8]; \
      sfrag bl =                                                               \
          *(const sfrag *)&wlds_lo[(size_t)((nt * NKK + (KKB) + j) * 64 + lane) * 8]; \
      acc0 = __builtin_amdgcn_mfma_f32_16x16x32_bf16(A[j], bh, acc0, 0, 0, 0); \
      acc1 = __builtin_amdgcn_mfma_f32_16x16x32_bf16(A[j], bl, acc1, 0, 0, 0); \
    }                                                                          \
  }

  for (int t = 0; t < Tv; ++t) {
    facc acc0 = {0.f, 0.f, 0.f, 0.f};
    facc acc1 = {0.f, 0.f, 0.f, 0.f};

    // ================= input half (off critical path) =================
    if (l == 0) {
      const float *xbp = p.x + ((size_t)m * Tv + t) * Iv + kgrp * 8;
#pragma unroll
      for (int kk = 0; kk < 8; ++kk) {
        f32x4 lo = *(const f32x4 *)(xbp + kk * 32);
        f32x4 hi = *(const f32x4 *)(xbp + kk * 32 + 4);
        sfrag ax;
#pragma unroll
        for (int j = 0; j < 4; ++j) {
          ax[j] = (short)f2bf(lo[j]);
          ax[4 + j] = (short)f2bf(hi[j]);
        }
        sfrag bh = *(const sfrag *)&wlds_hi[(size_t)((nt * NKK + 16 + kk) * 64 + lane) * 8];
        sfrag bl = *(const sfrag *)&wlds_lo[(size_t)((nt * NKK + 16 + kk) * 64 + lane) * 8];
        acc0 = __builtin_amdgcn_mfma_f32_16x16x32_bf16(ax, bh, acc0, 0, 0, 0);
        acc1 = __builtin_amdgcn_mfma_f32_16x16x32_bf16(ax, bl, acc1, 0, 0, 0);
      }
    } else {
      // h_{l-1}[t+1]: produced ~1 hop earlier; single-ushort poll
      poll_line(flags + ((size_t)(t * LAYv + (l - 1)) * 2 + mt) * 128 + lane * 2);
      const unsigned short *hin =
          hbuf + ((size_t)(((t + 1) & dmask) * LAYv + (l - 1)) * Bv * Hv) +
          (size_t)m * Hv;
      sfrag ain[16];
#pragma unroll
      for (int kk = 0; kk < 16; ++kk)
        ain[kk] = *(const sfrag *)(hin + kk * 32 + kgrp * 8);
      MFMA_BURST(ain, 16, 16)
    }

    // ================= recurrent half (critical path) =================
    if (t > 0) {
      poll_line(flags + ((size_t)((t - 1) * LAYv + l) * 2 + mt) * 128 + lane * 2);
      const unsigned short *hrec =
          hbuf + ((size_t)((t & dmask) * LAYv + l) * Bv * Hv) + (size_t)m * Hv;
      sfrag arec[16];
#pragma unroll
      for (int kk = 0; kk < 16; ++kk)
        arec[kk] = *(const sfrag *)(hrec + kk * 32 + kgrp * 8);
      MFMA_BURST(arec, 0, 16)
    } // t==0: h=0 contributes nothing

    // ---- scatter pre-activations to double-buffered LDS ----
    float *pa = pre0 + (t & 1) * PRE;
    {
      int row = mt * 16 + kgrp * 4;
      int coln = nt * 16 + (lane & 15);
#pragma unroll
      for (int r = 0; r < 4; ++r)
        pa[(row + r) * 33 + coln] = acc0[r] + acc1[r];
    }
    __syncthreads(); // the ONLY barrier per step

    // ---- gates / state update: one thread per (batch, unit) ----
    float pi = pa[bm * 33 + um * 4 + 0] + bia_i;
    float pf = pa[bm * 33 + um * 4 + 1] + bia_f;
    float po = pa[bm * 33 + um * 4 + 2] + bia_o;
    float pc = pa[bm * 33 + um * 4 + 3] + bia_c;
    float gi = 1.f / (1.f + __expf(-pi));
    float gf = 1.f / (1.f + __expf(-pf));
    float go = 1.f / (1.f + __expf(-po));
    float gc = tanhf(pc);
    cstate = gf * cstate + gi * gc;
    float hval = go * tanhf(cstate);

    // bypass store h[t+1]; per-WAVE drain; per-wave flag.
    // wave w's epilogue rows are w*8..w*8+7 -> half = w>>1, sub = w&1.
    st_short_bypass(
        &hbuf[((size_t)(((t + 1) & dmask) * LAYv + l) * Bv * Hv) +
              (size_t)bm * Hv + jg],
        f2bf(hval));
    asm volatile("s_waitcnt vmcnt(0)" ::: "memory"); // this wave's stores at MALL
    if (lane == 0)
      st_flagb_bypass(flags + ((size_t)(t * LAYv + l) * 2 + (w >> 1)) * 128 +
                      slice * 2 + (w & 1));

    if (l == LAYv - 1) // off critical path, after flag
      p.out[((size_t)bm * Tv + t) * Hv + jg] = hval;
  }
#undef MFMA_BURST
}

extern "C" void kernel_launch(void *const *d_in, const int *in_sizes, int n_in,
                              void *d_out, int out_size, void *d_ws, size_t ws_size,
                              hipStream_t stream) {
  Params prm;
  prm.x = (const float *)d_in[0];
  prm.Wx0i = (const float *)d_in[1];
  prm.Wx0f = (const float *)d_in[2];
  prm.Wx0o = (const float *)d_in[3];
  prm.Wx0c = (const float *)d_in[4];
  prm.Wxi = (const float *)d_in[5];
  prm.Wxf = (const float *)d_in[6];
  prm.Wxo = (const float *)d_in[7];
  prm.Wxc = (const float *)d_in[8];
  prm.Whi = (const float *)d_in[9];
  prm.Whf = (const float *)d_in[10];
  prm.Who = (const float *)d_in[11];
  prm.Whc = (const float *)d_in[12];
  prm.bi = (const float *)d_in[13];
  prm.bf = (const float *)d_in[14];
  prm.bo = (const float *)d_in[15];
  prm.bc = (const float *)d_in[16];
  prm.out = (float *)d_out;

  size_t slot_bytes = (size_t)LAYv * Bv * Hv * sizeof(unsigned short); // 128KB
  size_t fbytes = (size_t)Tv * LAYv * 2 * 128;                         // 512KB
  size_t hslots = 512; // exactly-once-read ring
  if (ws_size < hslots * slot_bytes + fbytes) {
    hslots = 256;
    if (ws_size < hslots * slot_bytes + fbytes) return;
  }
  prm.dmask = (int)hslots - 1;
  prm.hbuf = (unsigned short *)d_ws;
  prm.flags = (unsigned char *)d_ws + hslots * slot_bytes;

  // write-once flags, cleared every call (deterministic replays)
  hipMemsetAsync(prm.flags, 0, fbytes, stream);

  hipFuncSetAttribute(reinterpret_cast<const void *>(lstm_pipeline),
                      hipFuncAttributeMaxDynamicSharedMemorySize, (int)SMEM_BYTES);

  // Plain launch: 139.5KB LDS forces 1 block/CU; grid == 256 == #CUs.
  hipLaunchKernelGGL(lstm_pipeline, dim3(LAYv * SLICES), dim3(THREADS),
                     SMEM_BYTES, stream, prm);
}